// Round 1
// baseline (5116.679 us; speedup 1.0000x reference)
//
#include <hip/hip_runtime.h>
#include <hip/hip_bf16.h>
#include <math.h>

#define HEADS 8
#define CH    512     // C_IN == C_OUT
#define S     1024    // 32*32 spatial
#define NKV   320     // pooled kv length: 32 + 32 + 256
#define DH    64      // head dim
#define BATCH 32

// ws layout in floats
#define XP_OFF 0                               // xp  [B][512][320]
#define KV_OFF (XP_OFF + BATCH*CH*NKV)         // kv  [B][1024][320] (k rows 0..511, v rows 512..1023)
#define Q_OFF  (KV_OFF + BATCH*2*CH*NKV)       // q   [B][512][1024]
#define AO_OFF (Q_OFF  + BATCH*CH*S)           // ao  [B][512][1024]
#define PT_OFF (AO_OFF + BATCH*CH*S)           // posT[320][1024]
// total = 49,610,752 floats = 189.3 MiB

// ---------------------------------------------------------------------------
// Pool x: [B,C,32,32] -> [B,C,320]  (th mean-over-w | tw mean-over-h | 2x2 avg)
// One wave per (b,c) plane; plane staged in LDS.
// ---------------------------------------------------------------------------
__global__ __launch_bounds__(256) void pool_kernel(const float* __restrict__ x,
                                                   float* __restrict__ xp) {
    __shared__ float sm[4][1024];
    const int w = threadIdx.x >> 6;
    const int l = threadIdx.x & 63;
    const int p = blockIdx.x * 4 + w;          // plane = b*512 + c
    const float* src = x + (size_t)p * 1024;
    #pragma unroll
    for (int j = 0; j < 16; ++j) sm[w][j * 64 + l] = src[j * 64 + l];
    __syncthreads();
    float* dst = xp + (size_t)p * NKV;
    const float* pl = sm[w];
    #pragma unroll
    for (int g = 0; g < 5; ++g) {
        const int nn = g * 64 + l;             // 0..319
        float r;
        if (nn < 32) {                         // th[h] = mean over w
            const int h = nn; float s = 0.f;
            #pragma unroll
            for (int ww = 0; ww < 32; ++ww) s += pl[h * 32 + ww];
            r = s * (1.0f / 32.0f);
        } else if (nn < 64) {                  // tw[w] = mean over h
            const int ww = nn - 32; float s = 0.f;
            #pragma unroll
            for (int h = 0; h < 32; ++h) s += pl[h * 32 + ww];
            r = s * (1.0f / 32.0f);
        } else {                               // 2x2 avg pool, i = ph*16+pw
            const int i = nn - 64;
            const int ph = i >> 4, pw = i & 15;
            r = 0.25f * (pl[(2 * ph) * 32 + 2 * pw]     + pl[(2 * ph) * 32 + 2 * pw + 1] +
                         pl[(2 * ph + 1) * 32 + 2 * pw] + pl[(2 * ph + 1) * 32 + 2 * pw + 1]);
        }
        dst[nn] = r;
    }
}

// ---------------------------------------------------------------------------
// pos[1, s, n] -> posT[n, s]  (so attention reads are coalesced in s)
// ---------------------------------------------------------------------------
__global__ __launch_bounds__(256) void pos_transpose(const float* __restrict__ pos,
                                                     float* __restrict__ posT) {
    const int idx = blockIdx.x * 256 + threadIdx.x;   // over 320*1024
    const int n = idx >> 10, s = idx & 1023;
    posT[idx] = pos[s * NKV + n];
}

// ---------------------------------------------------------------------------
// C[bz][m][n] = act( sum_k W[m][k] * X[bz][k][n] (+ bias[m]) )
// ACT: 0 none, 1 sigmoid, 2 +bias. 64x64 tile, 256 thr, 4x4 per thread.
// ---------------------------------------------------------------------------
template <int ACT>
__global__ __launch_bounds__(256) void gemm_f32(const float* __restrict__ W,
                                                const float* __restrict__ X,
                                                const float* __restrict__ bias,
                                                float* __restrict__ C,
                                                int M, int N, int K) {
    __shared__ float As[16][68];   // As[k][m] (transposed on store)
    __shared__ float Bs[16][68];   // Bs[k][n]
    const int t  = threadIdx.x;
    const int tx = t & 15, ty = t >> 4;
    const int n0 = blockIdx.x * 64, m0 = blockIdx.y * 64;
    const float* Xb = X + (size_t)blockIdx.z * K * N;
    float acc[4][4] = {};
    for (int k0 = 0; k0 < K; k0 += 16) {
        {
            const int r = t >> 2, kc = (t & 3) << 2;
            const float4 a = *(const float4*)(W + (size_t)(m0 + r) * K + k0 + kc);
            As[kc + 0][r] = a.x; As[kc + 1][r] = a.y;
            As[kc + 2][r] = a.z; As[kc + 3][r] = a.w;
        }
        {
            const int kr = t >> 4, nc = (t & 15) << 2;
            const float4 bl = *(const float4*)(Xb + (size_t)(k0 + kr) * N + n0 + nc);
            *(float4*)&Bs[kr][nc] = bl;
        }
        __syncthreads();
        #pragma unroll
        for (int k = 0; k < 16; ++k) {
            const float4 a4 = *(const float4*)&As[k][ty << 2];
            const float4 b4 = *(const float4*)&Bs[k][tx << 2];
            const float av[4] = {a4.x, a4.y, a4.z, a4.w};
            const float bv[4] = {b4.x, b4.y, b4.z, b4.w};
            #pragma unroll
            for (int i = 0; i < 4; ++i)
                #pragma unroll
                for (int j = 0; j < 4; ++j)
                    acc[i][j] += av[i] * bv[j];
        }
        __syncthreads();
    }
    float* Cb = C + (size_t)blockIdx.z * M * N;
    #pragma unroll
    for (int i = 0; i < 4; ++i) {
        const int m = m0 + (ty << 2) + i;
        const float bsv = (ACT == 2) ? bias[m] : 0.0f;
        float4 o;
        float* oo = &o.x;
        #pragma unroll
        for (int j = 0; j < 4; ++j) {
            float v = acc[i][j];
            if (ACT == 2) v += bsv;
            if (ACT == 1) v = 1.0f / (1.0f + __expf(-v));
            oo[j] = v;
        }
        *(float4*)(Cb + (size_t)m * N + n0 + (tx << 2)) = o;
    }
}

// ---------------------------------------------------------------------------
// Attention: one thread per query row s (per b,h). Online softmax, NT=16.
// q stored [b][c][s]: per-dd loads coalesced across lanes (lane<->s).
// k/v addresses are wave-uniform -> compiler scalarizes to s_load (SGPR
// operands feed v_fmac directly, no LDS traffic).
// ---------------------------------------------------------------------------
__global__ __launch_bounds__(256) void attn_kernel(const float* __restrict__ q,
                                                   const float* __restrict__ kv,
                                                   const float* __restrict__ posT,
                                                   float* __restrict__ ao) {
    const int b = blockIdx.z, h = blockIdx.y;
    const int s = blockIdx.x * 256 + threadIdx.x;
    const float scale = 0.125f;  // 64^-0.5

    float qr[DH];
    const float* qp = q + ((size_t)b * CH + h * DH) * S + s;
    #pragma unroll
    for (int dd = 0; dd < DH; ++dd) qr[dd] = qp[(size_t)dd * S] * scale;

    const float* kp = kv + ((size_t)b * 2 * CH + h * DH) * NKV;  // k rows
    const float* vp = kp + (size_t)CH * NKV;                     // v rows

    float m = -1e30f, l = 0.0f;
    float acc[DH];
    #pragma unroll
    for (int dd = 0; dd < DH; ++dd) acc[dd] = 0.0f;

    for (int n0 = 0; n0 < NKV; n0 += 16) {
        float dt[16];
        #pragma unroll
        for (int nn = 0; nn < 16; ++nn) {
            const int n = n0 + nn;
            float d0 = 0.f, d1 = 0.f, d2 = 0.f, d3 = 0.f;
            #pragma unroll
            for (int dd = 0; dd < DH; dd += 4) {
                d0 += qr[dd + 0] * kp[(size_t)(dd + 0) * NKV + n];
                d1 += qr[dd + 1] * kp[(size_t)(dd + 1) * NKV + n];
                d2 += qr[dd + 2] * kp[(size_t)(dd + 2) * NKV + n];
                d3 += qr[dd + 3] * kp[(size_t)(dd + 3) * NKV + n];
            }
            dt[nn] = (d0 + d1) + (d2 + d3) + posT[(size_t)n * S + s];
        }
        float mt = dt[0];
        #pragma unroll
        for (int nn = 1; nn < 16; ++nn) mt = fmaxf(mt, dt[nn]);
        const float m_new = fmaxf(m, mt);
        const float alpha = __expf(m - m_new);
        float psum = 0.f;
        #pragma unroll
        for (int nn = 0; nn < 16; ++nn) {
            const float pv = __expf(dt[nn] - m_new);
            dt[nn] = pv; psum += pv;
        }
        l = l * alpha + psum;
        #pragma unroll
        for (int dd = 0; dd < DH; ++dd) acc[dd] *= alpha;
        #pragma unroll
        for (int nn = 0; nn < 16; ++nn) {
            const int n = n0 + nn;
            const float pv = dt[nn];
            #pragma unroll
            for (int dd = 0; dd < DH; ++dd)
                acc[dd] += pv * vp[(size_t)dd * NKV + n];
        }
        m = m_new;
    }
    const float inv_l = 1.0f / l;
    float* op = ao + ((size_t)b * CH + h * DH) * S + s;
    #pragma unroll
    for (int dd = 0; dd < DH; ++dd) op[(size_t)dd * S] = acc[dd] * inv_l;
}

// ---------------------------------------------------------------------------
extern "C" void kernel_launch(void* const* d_in, const int* in_sizes, int n_in,
                              void* d_out, int out_size, void* d_ws, size_t ws_size,
                              hipStream_t stream) {
    const float* x    = (const float*)d_in[0];
    const float* Wqkv = (const float*)d_in[1];
    const float* Wout = (const float*)d_in[2];
    const float* bout = (const float*)d_in[3];
    const float* pos  = (const float*)d_in[4];
    float* ws   = (float*)d_ws;
    float* xp   = ws + XP_OFF;
    float* kvp  = ws + KV_OFF;
    float* qws  = ws + Q_OFF;
    float* ao   = ws + AO_OFF;
    float* posT = ws + PT_OFF;
    float* out  = (float*)d_out;

    // 1) pool x -> xp  (conv and pool commute: pool(conv(x)) == conv(pool(x)))
    pool_kernel<<<dim3(BATCH * CH / 4), 256, 0, stream>>>(x, xp);
    // 2) transpose pos for coalesced access
    pos_transpose<<<dim3(NKV * S / 256), 256, 0, stream>>>(pos, posT);
    // 3) q conv: q = Wqkv[0:512] @ x[b]
    gemm_f32<0><<<dim3(S / 64, CH / 64, BATCH), 256, 0, stream>>>(
        Wqkv, x, nullptr, qws, CH, S, CH);
    // 4) kv conv on pooled x + sigmoid: kv = sigmoid(Wqkv[512:1536] @ xp[b])
    gemm_f32<1><<<dim3(NKV / 64, 2 * CH / 64, BATCH), 256, 0, stream>>>(
        Wqkv + CH * CH, xp, nullptr, kvp, 2 * CH, NKV, CH);
    // 5) attention
    attn_kernel<<<dim3(S / 256, HEADS, BATCH), 256, 0, stream>>>(qws, kvp, posT, ao);
    // 6) output projection + bias
    gemm_f32<2><<<dim3(S / 64, CH / 64, BATCH), 256, 0, stream>>>(
        Wout, ao, bout, out, CH, S, CH);
}

// Round 2
// 830.196 us; speedup vs baseline: 6.1632x; 6.1632x over previous
//
#include <hip/hip_runtime.h>
#include <hip/hip_bf16.h>
#include <math.h>

#define HEADS 8
#define CH    512     // C_IN == C_OUT
#define S     1024    // 32*32 spatial
#define NKV   320     // pooled kv length: 32 + 32 + 256
#define DH    64      // head dim
#define BATCH 32

// ws layout in floats
#define XP_OFF 0                               // xp  [B][512][320]
#define KV_OFF (XP_OFF + BATCH*CH*NKV)         // kv  [B][1024][320] (k rows 0..511, v rows 512..1023)
#define Q_OFF  (KV_OFF + BATCH*2*CH*NKV)       // q   [B][512][1024]
#define AO_OFF (Q_OFF  + BATCH*CH*S)           // ao  [B][512][1024]

typedef __attribute__((ext_vector_type(8))) short short8;
typedef __attribute__((ext_vector_type(4))) float float4v;

__device__ __forceinline__ short f2bf(float f) {
    __hip_bfloat16 h = __float2bfloat16(f);
    return *reinterpret_cast<short*>(&h);
}

// ---------------------------------------------------------------------------
// Pool x: [B,C,32,32] -> [B,C,320]  (th mean-over-w | tw mean-over-h | 2x2 avg)
// ---------------------------------------------------------------------------
__global__ __launch_bounds__(256) void pool_kernel(const float* __restrict__ x,
                                                   float* __restrict__ xp) {
    __shared__ float sm[4][1024];
    const int w = threadIdx.x >> 6;
    const int l = threadIdx.x & 63;
    const int p = blockIdx.x * 4 + w;          // plane = b*512 + c
    const float* src = x + (size_t)p * 1024;
    #pragma unroll
    for (int j = 0; j < 16; ++j) sm[w][j * 64 + l] = src[j * 64 + l];
    __syncthreads();
    float* dst = xp + (size_t)p * NKV;
    const float* pl = sm[w];
    #pragma unroll
    for (int g = 0; g < 5; ++g) {
        const int nn = g * 64 + l;             // 0..319
        float r;
        if (nn < 32) {
            const int h = nn; float s = 0.f;
            #pragma unroll
            for (int ww = 0; ww < 32; ++ww) s += pl[h * 32 + ww];
            r = s * (1.0f / 32.0f);
        } else if (nn < 64) {
            const int ww = nn - 32; float s = 0.f;
            #pragma unroll
            for (int h = 0; h < 32; ++h) s += pl[h * 32 + ww];
            r = s * (1.0f / 32.0f);
        } else {
            const int i = nn - 64;
            const int ph = i >> 4, pw = i & 15;
            r = 0.25f * (pl[(2 * ph) * 32 + 2 * pw]     + pl[(2 * ph) * 32 + 2 * pw + 1] +
                         pl[(2 * ph + 1) * 32 + 2 * pw] + pl[(2 * ph + 1) * 32 + 2 * pw + 1]);
        }
        dst[nn] = r;
    }
}

// ---------------------------------------------------------------------------
// C[bz][m][n] = act( sum_k W[m][k] * X[bz][k][n] (+ bias[m]) )
// ACT: 0 none, 1 sigmoid, 2 +bias. 64x64 tile, 256 thr, 4x4 per thread.
// ---------------------------------------------------------------------------
template <int ACT>
__global__ __launch_bounds__(256) void gemm_f32(const float* __restrict__ W,
                                                const float* __restrict__ X,
                                                const float* __restrict__ bias,
                                                float* __restrict__ C,
                                                int M, int N, int K) {
    __shared__ float As[16][68];
    __shared__ float Bs[16][68];
    const int t  = threadIdx.x;
    const int tx = t & 15, ty = t >> 4;
    const int n0 = blockIdx.x * 64, m0 = blockIdx.y * 64;
    const float* Xb = X + (size_t)blockIdx.z * K * N;
    float acc[4][4] = {};
    for (int k0 = 0; k0 < K; k0 += 16) {
        {
            const int r = t >> 2, kc = (t & 3) << 2;
            const float4 a = *(const float4*)(W + (size_t)(m0 + r) * K + k0 + kc);
            As[kc + 0][r] = a.x; As[kc + 1][r] = a.y;
            As[kc + 2][r] = a.z; As[kc + 3][r] = a.w;
        }
        {
            const int kr = t >> 4, nc = (t & 15) << 2;
            const float4 bl = *(const float4*)(Xb + (size_t)(k0 + kr) * N + n0 + nc);
            *(float4*)&Bs[kr][nc] = bl;
        }
        __syncthreads();
        #pragma unroll
        for (int k = 0; k < 16; ++k) {
            const float4 a4 = *(const float4*)&As[k][ty << 2];
            const float4 b4 = *(const float4*)&Bs[k][tx << 2];
            const float av[4] = {a4.x, a4.y, a4.z, a4.w};
            const float bv[4] = {b4.x, b4.y, b4.z, b4.w};
            #pragma unroll
            for (int i = 0; i < 4; ++i)
                #pragma unroll
                for (int j = 0; j < 4; ++j)
                    acc[i][j] += av[i] * bv[j];
        }
        __syncthreads();
    }
    float* Cb = C + (size_t)blockIdx.z * M * N;
    #pragma unroll
    for (int i = 0; i < 4; ++i) {
        const int m = m0 + (ty << 2) + i;
        const float bsv = (ACT == 2) ? bias[m] : 0.0f;
        float4 o;
        float* oo = &o.x;
        #pragma unroll
        for (int j = 0; j < 4; ++j) {
            float v = acc[i][j];
            if (ACT == 2) v += bsv;
            if (ACT == 1) v = 1.0f / (1.0f + __expf(-v));
            oo[j] = v;
        }
        *(float4*)(Cb + (size_t)m * N + n0 + (tx << 2)) = o;
    }
}

// ---------------------------------------------------------------------------
// MFMA attention. Block = 512 thr (8 waves) per (b, h, 128-row s-tile).
// Each wave owns 16 query rows; all 320 scores live in 20 C-layout acc tiles.
// LDS: smA = per-wave 16x72 region (Q rows -> P chunks -> O staging),
//      smB = K [320][72] then (after barrier) V^T [64][328].
// A-frag: A[m=lane&15][k=quad*8+j]; B-frag: B[k=quad*8+j][n=lane&15];
// C/D: col=lane&15, row=quad*4+reg  (m89/m91/m120 verified layouts).
// ---------------------------------------------------------------------------
__global__ __launch_bounds__(512) void attn_mfma(const float* __restrict__ q,
                                                 const float* __restrict__ kv,
                                                 const float* __restrict__ pos,
                                                 float* __restrict__ ao) {
    __shared__ short smA[8 * 16 * 72];    // 18432 B
    __shared__ short smB[320 * 72];       // 46080 B (V^T view: [64][328] = 41984 B)
    const int tid  = threadIdx.x;
    const int w    = tid >> 6;
    const int lane = tid & 63;
    const int quad = lane >> 4, m = lane & 15;
    const int b = blockIdx.z, h = blockIdx.y, sb = blockIdx.x;
    const int s0 = sb * 128;

    // ---- stage Q (x 0.125, exact pow2) as [s][72] bf16 ----
    for (int i = tid; i < 1024; i += 512) {
        const int s = i & 127, dg = i >> 7;           // dg: 0..7
        const float* src = q + (((size_t)(b * CH + h * DH + dg * 8)) << 10) + s0 + s;
        short8 v;
        #pragma unroll
        for (int e = 0; e < 8; ++e) v[e] = f2bf(src[(size_t)e << 10] * 0.125f);
        *(short8*)&smA[s * 72 + dg * 8] = v;
    }
    // ---- stage K as [n][72] bf16 (transpose from kv's [d][n]) ----
    for (int i = tid; i < 2560; i += 512) {
        const int n = i % 320, dg = i / 320;
        const float* src = kv + (size_t)(b * 2 * CH + h * DH + dg * 8) * NKV + n;
        short8 v;
        #pragma unroll
        for (int e = 0; e < 8; ++e) v[e] = f2bf(src[e * NKV]);
        *(short8*)&smB[n * 72 + dg * 8] = v;
    }
    __syncthreads();

    short* Qw = &smA[w * 16 * 72];        // this wave's private 16x72 region
    const short8 aQ0 = *(const short8*)&Qw[m * 72 + quad * 8];
    const short8 aQ1 = *(const short8*)&Qw[m * 72 + 32 + quad * 8];

    const float4v zero = {0.f, 0.f, 0.f, 0.f};
    float4v acc[20];
    #pragma unroll
    for (int t = 0; t < 20; ++t) acc[t] = zero;

    // ---- QK^T: Sc[s][n], 20 n-tiles x 2 k-steps ----
    #pragma unroll
    for (int t = 0; t < 20; ++t) {
        const short8 b0 = *(const short8*)&smB[(t * 16 + m) * 72 + quad * 8];
        const short8 b1 = *(const short8*)&smB[(t * 16 + m) * 72 + 32 + quad * 8];
        acc[t] = __builtin_amdgcn_mfma_f32_16x16x32_bf16(aQ0, b0, acc[t], 0, 0, 0);
        acc[t] = __builtin_amdgcn_mfma_f32_16x16x32_bf16(aQ1, b1, acc[t], 0, 0, 0);
    }

    // ---- + pos, row max ----
    const int srow = s0 + w * 16 + quad * 4;
    float mrow[4] = {-1e30f, -1e30f, -1e30f, -1e30f};
    #pragma unroll
    for (int t = 0; t < 20; ++t) {
        #pragma unroll
        for (int r = 0; r < 4; ++r) {
            const float sc = acc[t][r] + pos[(size_t)(srow + r) * NKV + t * 16 + m];
            acc[t][r] = sc;
            mrow[r] = fmaxf(mrow[r], sc);
        }
    }
    #pragma unroll
    for (int r = 0; r < 4; ++r) {
        #pragma unroll
        for (int off = 1; off < 16; off <<= 1)
            mrow[r] = fmaxf(mrow[r], __shfl_xor(mrow[r], off, 16));
    }
    // ---- exp + row sum ----
    float lrow[4] = {0.f, 0.f, 0.f, 0.f};
    #pragma unroll
    for (int t = 0; t < 20; ++t) {
        #pragma unroll
        for (int r = 0; r < 4; ++r) {
            const float p = __expf(acc[t][r] - mrow[r]);
            acc[t][r] = p;
            lrow[r] += p;
        }
    }
    #pragma unroll
    for (int r = 0; r < 4; ++r) {
        #pragma unroll
        for (int off = 1; off < 16; off <<= 1)
            lrow[r] += __shfl_xor(lrow[r], off, 16);
    }

    __syncthreads();   // all waves done reading K from smB

    // ---- restage V^T as [d][328] bf16 (kv's v part is already [d][n]) ----
    for (int i = tid; i < 2560; i += 512) {
        const int d = i / 40, n8 = i % 40;
        const float* src = kv + (size_t)(b * 2 * CH + CH + h * DH + d) * NKV + n8 * 8;
        const float4 u0 = *(const float4*)src;
        const float4 u1 = *(const float4*)(src + 4);
        short8 v;
        v[0] = f2bf(u0.x); v[1] = f2bf(u0.y); v[2] = f2bf(u0.z); v[3] = f2bf(u0.w);
        v[4] = f2bf(u1.x); v[5] = f2bf(u1.y); v[6] = f2bf(u1.z); v[7] = f2bf(u1.w);
        *(short8*)&smB[d * 328 + n8 * 8] = v;
    }
    __syncthreads();

    // ---- P@V, P chunks (64 n) round-trip through wave-private LDS ----
    short* Pw = Qw;   // Q rows dead (A-frags already in regs); reuse
    float4v O[4];
    #pragma unroll
    for (int dt = 0; dt < 4; ++dt) O[dt] = zero;
    #pragma unroll
    for (int c = 0; c < 5; ++c) {
        #pragma unroll
        for (int tt = 0; tt < 4; ++tt) {
            #pragma unroll
            for (int r = 0; r < 4; ++r)
                Pw[(quad * 4 + r) * 72 + tt * 16 + m] = f2bf(acc[4 * c + tt][r]);
        }
        #pragma unroll
        for (int ks = 0; ks < 2; ++ks) {
            const short8 aP = *(const short8*)&Pw[m * 72 + ks * 32 + quad * 8];
            #pragma unroll
            for (int dt = 0; dt < 4; ++dt) {
                const short8 bV = *(const short8*)&smB[(dt * 16 + m) * 328 + c * 64 + ks * 32 + quad * 8];
                O[dt] = __builtin_amdgcn_mfma_f32_16x16x32_bf16(aP, bV, O[dt], 0, 0, 0);
            }
        }
    }

    // ---- normalize, emit ao[b][c][s] fp32 coalesced via LDS round-trip ----
    float inv[4];
    #pragma unroll
    for (int r = 0; r < 4; ++r) inv[r] = 1.0f / lrow[r];
    #pragma unroll
    for (int dt = 0; dt < 4; ++dt)
        #pragma unroll
        for (int r = 0; r < 4; ++r) O[dt][r] *= inv[r];

    float* Of = (float*)Pw;               // [16][33] fp32 = 2112 B <= 2304 B
    float* aob = ao + (((size_t)(b * CH + h * DH)) << 10) + s0 + w * 16;
    #pragma unroll
    for (int p = 0; p < 2; ++p) {
        #pragma unroll
        for (int dt2 = 0; dt2 < 2; ++dt2) {
            #pragma unroll
            for (int r = 0; r < 4; ++r)
                Of[(quad * 4 + r) * 33 + dt2 * 16 + m] = O[2 * p + dt2][r];
        }
        #pragma unroll
        for (int i = 0; i < 8; ++i) {
            const int dcol = i * 4 + quad;
            const float val = Of[m * 33 + dcol];
            aob[((size_t)(p * 32 + dcol) << 10) + m] = val;
        }
    }
}

// ---------------------------------------------------------------------------
extern "C" void kernel_launch(void* const* d_in, const int* in_sizes, int n_in,
                              void* d_out, int out_size, void* d_ws, size_t ws_size,
                              hipStream_t stream) {
    const float* x    = (const float*)d_in[0];
    const float* Wqkv = (const float*)d_in[1];
    const float* Wout = (const float*)d_in[2];
    const float* bout = (const float*)d_in[3];
    const float* pos  = (const float*)d_in[4];
    float* ws  = (float*)d_ws;
    float* xp  = ws + XP_OFF;
    float* kvp = ws + KV_OFF;
    float* qws = ws + Q_OFF;
    float* ao  = ws + AO_OFF;
    float* out = (float*)d_out;

    // 1) pool x -> xp  (pool(conv(x)) == conv(pool(x)))
    pool_kernel<<<dim3(BATCH * CH / 4), 256, 0, stream>>>(x, xp);
    // 2) q conv: q = Wqkv[0:512] @ x[b]
    gemm_f32<0><<<dim3(S / 64, CH / 64, BATCH), 256, 0, stream>>>(
        Wqkv, x, nullptr, qws, CH, S, CH);
    // 3) kv conv on pooled x + sigmoid
    gemm_f32<1><<<dim3(NKV / 64, 2 * CH / 64, BATCH), 256, 0, stream>>>(
        Wqkv + CH * CH, xp, nullptr, kvp, 2 * CH, NKV, CH);
    // 4) MFMA attention
    attn_mfma<<<dim3(S / 128, HEADS, BATCH), 512, 0, stream>>>(qws, kvp, pos, ao);
    // 5) output projection + bias
    gemm_f32<2><<<dim3(S / 64, CH / 64, BATCH), 256, 0, stream>>>(
        Wout, ao, bout, out, CH, S, CH);
}

// Round 3
// 309.615 us; speedup vs baseline: 16.5259x; 2.6814x over previous
//
#include <hip/hip_runtime.h>
#include <hip/hip_bf16.h>
#include <math.h>

#define HEADS 8
#define CH    512
#define S     1024
#define NKV   320
#define DH    64
#define BATCH 32

typedef __attribute__((ext_vector_type(8))) short short8;
typedef __attribute__((ext_vector_type(4))) short short4v;
typedef __attribute__((ext_vector_type(4))) float float4v;

__device__ __forceinline__ short f2bf(float f) {
    __hip_bfloat16 h = __float2bfloat16(f);
    return *reinterpret_cast<short*>(&h);
}

// async global->LDS DMA, 16B/lane. LDS base must be wave-uniform; HW adds lane*16.
#define GLOAD_LDS16(gp, lp) __builtin_amdgcn_global_load_lds( \
    (const __attribute__((address_space(1))) void*)(gp),      \
    (__attribute__((address_space(3))) void*)(lp), 16, 0, 0)

// ---------------------------------------------------------------------------
// Pool x: [B,C,32,32] -> xp [B,C,320] fp32 (mean-w | mean-h | 2x2 avg)
// ---------------------------------------------------------------------------
__global__ __launch_bounds__(256) void pool_kernel(const float* __restrict__ x,
                                                   float* __restrict__ xp) {
    __shared__ float sm[4][1024];
    const int w = threadIdx.x >> 6;
    const int l = threadIdx.x & 63;
    const int p = blockIdx.x * 4 + w;
    const float* src = x + (size_t)p * 1024;
    #pragma unroll
    for (int j = 0; j < 16; ++j) sm[w][j * 64 + l] = src[j * 64 + l];
    __syncthreads();
    float* dst = xp + (size_t)p * NKV;
    const float* pl = sm[w];
    #pragma unroll
    for (int g = 0; g < 5; ++g) {
        const int nn = g * 64 + l;
        float r;
        if (nn < 32) {
            const int h = nn; float s = 0.f;
            #pragma unroll
            for (int ww = 0; ww < 32; ++ww) s += pl[h * 32 + ww];
            r = s * (1.0f / 32.0f);
        } else if (nn < 64) {
            const int ww = nn - 32; float s = 0.f;
            #pragma unroll
            for (int h = 0; h < 32; ++h) s += pl[h * 32 + ww];
            r = s * (1.0f / 32.0f);
        } else {
            const int i = nn - 64;
            const int ph = i >> 4, pw = i & 15;
            r = 0.25f * (pl[(2 * ph) * 32 + 2 * pw]     + pl[(2 * ph) * 32 + 2 * pw + 1] +
                         pl[(2 * ph + 1) * 32 + 2 * pw] + pl[(2 * ph + 1) * 32 + 2 * pw + 1]);
        }
        dst[nn] = r;
    }
}

// ---------------------------------------------------------------------------
// Transpose-cast: in [bz][R][C] fp32 -> out [bz][C][R] bf16. grid (C/64, R/64, B)
// ---------------------------------------------------------------------------
__global__ __launch_bounds__(256) void tcast(const float* __restrict__ in,
                                             short* __restrict__ out, int R, int C) {
    __shared__ float sm[64][65];
    const int t = threadIdx.x;
    const int c0 = blockIdx.x * 64, r0 = blockIdx.y * 64;
    const float* ib = in + ((size_t)blockIdx.z * R + r0) * C + c0;
    #pragma unroll
    for (int rep = 0; rep < 4; ++rep) {
        const int r = rep * 16 + (t >> 4), c = (t & 15) * 4;
        const float4 v = *(const float4*)&ib[(size_t)r * C + c];
        sm[r][c] = v.x; sm[r][c + 1] = v.y; sm[r][c + 2] = v.z; sm[r][c + 3] = v.w;
    }
    __syncthreads();
    short* ob = out + ((size_t)blockIdx.z * C + c0) * R + r0;
    #pragma unroll
    for (int rep = 0; rep < 4; ++rep) {
        const int cr = rep * 16 + (t >> 4), rc = (t & 15) * 4;
        short4v p;
        #pragma unroll
        for (int e = 0; e < 4; ++e) p[e] = f2bf(sm[rc + e][cr]);
        *(short4v*)&ob[(size_t)cr * R + rc] = p;
    }
}

// ---------------------------------------------------------------------------
// Flat fp32 -> bf16 cast (weights). n divisible by 4.
// ---------------------------------------------------------------------------
__global__ __launch_bounds__(256) void castw(const float* __restrict__ in,
                                             short* __restrict__ out, int n) {
    const int i = (blockIdx.x * 256 + threadIdx.x) * 4;
    if (i < n) {
        const float4 v = *(const float4*)&in[i];
        short4v p = {f2bf(v.x), f2bf(v.y), f2bf(v.z), f2bf(v.w)};
        *(short4v*)&out[i] = p;
    }
}

// ---------------------------------------------------------------------------
// bf16 MFMA GEMM: Out[bz][row][col] = act( sum_k A[bz][row][k]*B[bz][col][k] )
// A [*,M,K], B [*,N,K] both K-contiguous bf16, K=512. 256 thr = 4 waves (2x2),
// wave tile (MT*16)x(NT*16), block tile BM=32*MT x BN=32*NT, BK=64.
// Staging via global_load_lds(16B) into XOR-swizzled packed LDS rows:
// physical chunk pc of row r holds logical chunk pc^(r&7) -> b128 frag reads
// are 2-way-conflict-free. ACT: 0 none(bf16), 1 sigmoid+0.125 on col<512(bf16),
// 2 +bias[row] (fp32 out).
// ---------------------------------------------------------------------------
template <int MT, int NT, int ACT, typename OT>
__global__ __launch_bounds__(256) void gemm_bf16(const short* __restrict__ A, long sAb,
                                                 const short* __restrict__ B, long sBb,
                                                 const float* __restrict__ bias,
                                                 OT* __restrict__ C, int M, int N) {
    constexpr int K  = 512;
    constexpr int BM = 32 * MT, BN = 32 * NT;
    __shared__ short As[BM * 64];
    __shared__ short Bs[BN * 64];
    const int t = threadIdx.x, w = t >> 6, l = t & 63;
    const int wm = w >> 1, wn = w & 1, quad = l >> 4, m15 = l & 15;
    const int bz = blockIdx.z;
    const int n0 = blockIdx.x * BN, m0 = blockIdx.y * BM;
    const short* gA = A + (size_t)sAb * bz + (size_t)m0 * K;
    const short* gB = B + (size_t)sBb * bz + (size_t)n0 * K;
    const int lrow = l >> 3;     // row within an 8-row staging group
    const int pc   = l & 7;      // physical 16B chunk within row

    const float4v zf = {0.f, 0.f, 0.f, 0.f};
    float4v acc[MT][NT];
    #pragma unroll
    for (int i = 0; i < MT; ++i)
        #pragma unroll
        for (int j = 0; j < NT; ++j) acc[i][j] = zf;

    for (int k0 = 0; k0 < K; k0 += 64) {
        #pragma unroll
        for (int ii = w; ii < BM / 8; ii += 4) {
            const int row = ii * 8 + lrow;
            const int x = pc ^ (row & 7);
            GLOAD_LDS16(gA + (size_t)row * K + k0 + x * 8, &As[ii * 512]);
        }
        #pragma unroll
        for (int ii = w; ii < BN / 8; ii += 4) {
            const int row = ii * 8 + lrow;
            const int x = pc ^ (row & 7);
            GLOAD_LDS16(gB + (size_t)row * K + k0 + x * 8, &Bs[ii * 512]);
        }
        __syncthreads();
        #pragma unroll
        for (int ks = 0; ks < 2; ++ks) {
            const int xa = (((ks * 4 + quad) ^ (m15 & 7))) * 8;
            short8 aF[MT], bF[NT];
            #pragma unroll
            for (int i = 0; i < MT; ++i)
                aF[i] = *(const short8*)&As[((wm * MT + i) * 16 + m15) * 64 + xa];
            #pragma unroll
            for (int j = 0; j < NT; ++j)
                bF[j] = *(const short8*)&Bs[((wn * NT + j) * 16 + m15) * 64 + xa];
            #pragma unroll
            for (int i = 0; i < MT; ++i)
                #pragma unroll
                for (int j = 0; j < NT; ++j)
                    acc[i][j] = __builtin_amdgcn_mfma_f32_16x16x32_bf16(aF[i], bF[j], acc[i][j], 0, 0, 0);
        }
        __syncthreads();
    }

    OT* gC = C + (size_t)bz * M * N;
    #pragma unroll
    for (int i = 0; i < MT; ++i) {
        #pragma unroll
        for (int r = 0; r < 4; ++r) {
            const int row = m0 + (wm * MT + i) * 16 + quad * 4 + r;
            float bv = 0.f;
            if (ACT == 2) bv = bias[row];
            #pragma unroll
            for (int j = 0; j < NT; ++j) {
                const int col = n0 + (wn * NT + j) * 16 + m15;
                float v = acc[i][j][r];
                if (ACT == 1) { v = 1.0f / (1.0f + __expf(-v)); if (col < 512) v *= 0.125f; }
                if (ACT == 2) v += bv;
                if constexpr (sizeof(OT) == 2)
                    ((short*)gC)[(size_t)row * N + col] = f2bf(v);
                else
                    ((float*)gC)[(size_t)row * N + col] = v;
            }
        }
    }
}

// ---------------------------------------------------------------------------
// MFMA attention. Block = 8 waves per (b, h, 128-row s-tile). qT [b][s][c] bf16
// (Q A-frags direct from global), kvT [b][n][ckv] bf16 (k cols<512 pre-scaled
// 0.125; v cols 512+). K staged via global_load_lds into [dg][320][8] (2-way
// free). V^T restaged [64][344] (2-way free). P roundtrips wave-private LDS.
// Output aoT [b][s][c] bf16 direct from frags.
// ---------------------------------------------------------------------------
__global__ __launch_bounds__(512) void attn_mfma(const short* __restrict__ qT,
                                                 const short* __restrict__ kvT,
                                                 const float* __restrict__ pos,
                                                 short* __restrict__ aoT) {
    __shared__ short smP[8 * 16 * 72];    // 18432 B: per-wave P/Q roundtrip
    __shared__ short smB[64 * 344];       // 44032 B: K [8][320][8] then V^T [64][344]
    const int tid = threadIdx.x, w = tid >> 6, l = tid & 63;
    const int quad = l >> 4, m15 = l & 15;
    const int b = blockIdx.z, h = blockIdx.y, s0 = blockIdx.x * 128;
    const short* kvb = kvT + (size_t)b * NKV * 1024;

    // ---- stage K: smB[dg][n][8] via global_load_lds (packed lane order) ----
    for (int i2 = w; i2 < 40; i2 += 8) {
        const int nb = i2 % 5, dg = i2 / 5;
        GLOAD_LDS16(kvb + (size_t)(nb * 64 + l) * 1024 + h * 64 + dg * 8,
                    &smB[(dg * 320 + nb * 64) * 8]);
    }
    // ---- Q A-frags straight from global (k-scale folded into kv GEMM) ----
    const short* qb = qT + (size_t)(b * S + s0 + w * 16 + m15) * 512 + h * 64;
    const short8 aQ0 = *(const short8*)&qb[quad * 8];
    const short8 aQ1 = *(const short8*)&qb[32 + quad * 8];
    __syncthreads();

    const float4v zf = {0.f, 0.f, 0.f, 0.f};
    float4v acc[20];
    #pragma unroll
    for (int tt = 0; tt < 20; ++tt) acc[tt] = zf;

    #pragma unroll
    for (int tt = 0; tt < 20; ++tt) {
        const short8 b0 = *(const short8*)&smB[(quad * 320 + tt * 16 + m15) * 8];
        const short8 b1 = *(const short8*)&smB[((4 + quad) * 320 + tt * 16 + m15) * 8];
        acc[tt] = __builtin_amdgcn_mfma_f32_16x16x32_bf16(aQ0, b0, acc[tt], 0, 0, 0);
        acc[tt] = __builtin_amdgcn_mfma_f32_16x16x32_bf16(aQ1, b1, acc[tt], 0, 0, 0);
    }

    // ---- + pos, row max, exp, row sum ----
    const int srow = s0 + w * 16 + quad * 4;
    float mrow[4] = {-1e30f, -1e30f, -1e30f, -1e30f};
    #pragma unroll
    for (int tt = 0; tt < 20; ++tt) {
        #pragma unroll
        for (int r = 0; r < 4; ++r) {
            const float sc = acc[tt][r] + pos[(size_t)(srow + r) * NKV + tt * 16 + m15];
            acc[tt][r] = sc;
            mrow[r] = fmaxf(mrow[r], sc);
        }
    }
    #pragma unroll
    for (int r = 0; r < 4; ++r) {
        #pragma unroll
        for (int off = 1; off < 16; off <<= 1)
            mrow[r] = fmaxf(mrow[r], __shfl_xor(mrow[r], off, 16));
    }
    float lrow[4] = {0.f, 0.f, 0.f, 0.f};
    #pragma unroll
    for (int tt = 0; tt < 20; ++tt) {
        #pragma unroll
        for (int r = 0; r < 4; ++r) {
            const float p = __expf(acc[tt][r] - mrow[r]);
            acc[tt][r] = p;
            lrow[r] += p;
        }
    }
    #pragma unroll
    for (int r = 0; r < 4; ++r) {
        #pragma unroll
        for (int off = 1; off < 16; off <<= 1)
            lrow[r] += __shfl_xor(lrow[r], off, 16);
    }

    __syncthreads();   // all waves done reading K from smB

    // ---- restage V^T [64][344] from kvT cols 512+ ----
    for (int it = 0; it < 5; ++it) {
        const int i2 = it * 512 + tid;
        const int n5 = i2 & 31, d8 = (i2 >> 5) & 7, nb = i2 >> 8;
        const int n = nb * 32 + n5;
        const short8 v = *(const short8*)&kvb[(size_t)n * 1024 + 512 + h * 64 + d8 * 8];
        #pragma unroll
        for (int e = 0; e < 8; ++e) smB[(d8 * 8 + e) * 344 + n] = v[e];
    }
    __syncthreads();

    // ---- P@V: P chunks via wave-private LDS; V^T B-frags from smB ----
    short* Pw = &smP[w * 16 * 72];
    float4v O[4];
    #pragma unroll
    for (int dt = 0; dt < 4; ++dt) O[dt] = zf;
    #pragma unroll
    for (int c = 0; c < 5; ++c) {
        #pragma unroll
        for (int tt = 0; tt < 4; ++tt) {
            #pragma unroll
            for (int r = 0; r < 4; ++r)
                Pw[(quad * 4 + r) * 72 + tt * 16 + m15] = f2bf(acc[4 * c + tt][r]);
        }
        #pragma unroll
        for (int ks = 0; ks < 2; ++ks) {
            const short8 aP = *(const short8*)&Pw[m15 * 72 + ks * 32 + quad * 8];
            #pragma unroll
            for (int dt = 0; dt < 4; ++dt) {
                const short8 bV = *(const short8*)&smB[(dt * 16 + m15) * 344 + c * 64 + ks * 32 + quad * 8];
                O[dt] = __builtin_amdgcn_mfma_f32_16x16x32_bf16(aP, bV, O[dt], 0, 0, 0);
            }
        }
    }

    // ---- normalize + direct bf16 output aoT[b][s][c] ----
    float inv[4];
    #pragma unroll
    for (int r = 0; r < 4; ++r) inv[r] = 1.0f / lrow[r];
    #pragma unroll
    for (int dt = 0; dt < 4; ++dt) {
        #pragma unroll
        for (int r = 0; r < 4; ++r) {
            const int s = s0 + w * 16 + quad * 4 + r;
            aoT[(size_t)(b * S + s) * 512 + h * 64 + dt * 16 + m15] = f2bf(O[dt][r] * inv[r]);
        }
    }
}

// ---------------------------------------------------------------------------
extern "C" void kernel_launch(void* const* d_in, const int* in_sizes, int n_in,
                              void* d_out, int out_size, void* d_ws, size_t ws_size,
                              hipStream_t stream) {
    const float* x    = (const float*)d_in[0];
    const float* Wqkv = (const float*)d_in[1];
    const float* Wout = (const float*)d_in[2];
    const float* bout = (const float*)d_in[3];
    const float* pos  = (const float*)d_in[4];
    char* ws = (char*)d_ws;
    float* xp   = (float*)(ws + 0);            // [32][512][320] f32   20971520 B
    short* xT   = (short*)(ws + 20971520);     // [32][1024][512] bf16 33554432 B
    short* xpT  = (short*)(ws + 54525952);     // [32][320][512] bf16  10485760 B
    short* qT   = (short*)(ws + 65011712);     // [32][1024][512] bf16 33554432 B
    short* kvT  = (short*)(ws + 98566144);     // [32][320][1024] bf16 20971520 B
    short* aoT  = (short*)(ws + 119537664);    // [32][1024][512] bf16 33554432 B
    short* Wbf  = (short*)(ws + 153092096);    // [1536][512] bf16      1572864 B
    short* Wobf = (short*)(ws + 154664960);    // [512][512] bf16        524288 B
    float* out  = (float*)d_out;

    castw<<<dim3(768), 256, 0, stream>>>(Wqkv, Wbf, 1536 * 512);
    castw<<<dim3(256), 256, 0, stream>>>(Wout, Wobf, 512 * 512);
    pool_kernel<<<dim3(BATCH * CH / 4), 256, 0, stream>>>(x, xp);
    tcast<<<dim3(16, 8, BATCH), 256, 0, stream>>>(x, xT, CH, S);       // -> xT [s][c]
    tcast<<<dim3(5, 8, BATCH), 256, 0, stream>>>(xp, xpT, CH, NKV);    // -> xpT [n][c]
    // qT[b][s][c] = xT . Wq
    gemm_bf16<4, 4, 0, short><<<dim3(4, 8, BATCH), 256, 0, stream>>>(
        xT, (long)S * CH, Wbf, 0, nullptr, qT, S, CH);
    // kvT[b][n][ckv] = sigmoid(xpT . Wkv), k-cols pre-scaled 0.125
    gemm_bf16<2, 8, 1, short><<<dim3(4, 5, BATCH), 256, 0, stream>>>(
        xpT, (long)NKV * CH, Wbf + CH * CH, 0, nullptr, kvT, NKV, 2 * CH);
    attn_mfma<<<dim3(8, HEADS, BATCH), 512, 0, stream>>>(qT, kvT, pos, aoT);
    // out[b][c][s] = Wout . aoT + bout  (fp32, direct coalesced)
    gemm_bf16<4, 4, 2, float><<<dim3(8, 4, BATCH), 256, 0, stream>>>(
        Wobf, 0, aoT, (long)S * CH, bout, out, CH, S);
}